// Round 5
// baseline (194.684 us; speedup 1.0000x reference)
//
#include <hip/hip_runtime.h>

// Problem constants (match reference)
#define N_TOKENS 16384
#define IN_F 1024
#define OUT_F 1024
#define NB 256      // sparse blocks
#define BH 32
#define BW 32
#define NRB 32      // OUT_F / BH
#define T_TILE 64   // tokens per workgroup (2 groups of 32 for 32x32 MFMA)
#define NWAVES 16   // 1024 threads
#define NBUCKET 16  // schedule buckets == waves
#define XS_STRIDE 1040           // shorts/row; proven 0-conflict stride (R3/R4 measured)
#define SCHED_ALLOC 304          // 288 max real entries + overread pads
#define WF_SLOT_SHORTS 1024      // per entry: 2 k-half frags x 64 lanes x 8 bf16 = 2048 B
#define FLUSH_BIT (1 << 10)

// Workspace layout (bytes). Total ~625 KB.
#define WS_WF_BYTES   (SCHED_ALLOC * WF_SLOT_SHORTS * 2)   // 622592
#define WS_SCHED_OFF  WS_WF_BYTES                           // int[SCHED_ALLOC]
#define WS_POS_OFF    (WS_SCHED_OFF + SCHED_ALLOC * 4)      // int[NB]
#define WS_WSTART_OFF (WS_POS_OFF + NB * 4)                 // int[NBUCKET+1]

typedef short short8 __attribute__((ext_vector_type(8)));     // MFMA A/B frag (8 bf16)
typedef float float16v __attribute__((ext_vector_type(16)));  // 32x32 MFMA C/D frag

// fp32 -> bf16 round-to-nearest-even (inputs finite)
__device__ __forceinline__ short f2bf(float f) {
    unsigned u = __builtin_bit_cast(unsigned, f);
    u += 0x7fffu + ((u >> 16) & 1u);
    return (short)(u >> 16);
}

// ---------------------------------------------------------------------------
// Prep 1 (256 thr): deterministic schedule in 16 balanced buckets.
// Rows sorted desc by entry count (empty rows count as 1 flush-only entry);
// bucket b gets rows ord[b] and ord[31-b] -> near-equal entry counts.
// Entry pack: bits[4:0]=c, bits[9:5]=r, bit[10]=flush (last entry of row).
// Slot of block b within its row = #{b'<b : row[b']==row[b]} (deterministic,
// so prep_w's pos_of agrees). Empty rows get a zeroed wf slot (their entry
// still runs 4 MFMAs -> must accumulate zero). 2 overread pad slots.
// ---------------------------------------------------------------------------
__global__ void prep_sched_kernel(const int* __restrict__ brow, const int* __restrict__ bcol,
                                  int* __restrict__ sched, int* __restrict__ pos_of,
                                  int* __restrict__ wstart, short* __restrict__ wf)
{
    __shared__ int cnt[NRB], rstart[NRB];
    __shared__ short srow[NB];
    const int tid = threadIdx.x;   // 256 threads, one per sparse block
    if (tid < NRB) cnt[tid] = 0;
    __syncthreads();
    const int r = brow[tid];
    const int c = bcol[tid];
    srow[tid] = (short)r;
    atomicAdd(&cnt[r], 1);
    __syncthreads();
    if (tid == 0) {
        int adj[NRB], ord[NRB];
        for (int i = 0; i < NRB; ++i) { adj[i] = cnt[i] ? cnt[i] : 1; ord[i] = i; }
        for (int i = 0; i < NRB - 1; ++i) {       // selection sort, desc by adj
            int m = i;
            for (int j = i + 1; j < NRB; ++j) if (adj[ord[j]] > adj[ord[m]]) m = j;
            const int t = ord[i]; ord[i] = ord[m]; ord[m] = t;
        }
        int pos = 0;
        for (int b = 0; b < NBUCKET; ++b) {       // pair largest with smallest
            wstart[b] = pos;
            const int r1 = ord[b], r2 = ord[31 - b];
            rstart[r1] = pos; pos += adj[r1];
            rstart[r2] = pos; pos += adj[r2];
        }
        wstart[NBUCKET] = pos;
        sched[pos] = 0; sched[pos + 1] = 0;       // overread pads (no flush bit)
    }
    __syncthreads();
    int slot = 0;                                 // deterministic within-row slot
    for (int b2 = 0; b2 < tid; ++b2) slot += (srow[b2] == r);
    const int pos = rstart[r] + slot;
    sched[pos] = c | (r << 5) | ((slot == cnt[r] - 1) ? FLUSH_BIT : 0);
    pos_of[tid] = pos;
    if (tid < NRB && cnt[tid] == 0) {             // empty-row: flush-only, zero W
        sched[rstart[tid]] = (tid << 5) | FLUSH_BIT;
        int4 z = {0, 0, 0, 0};
        int4* dst = (int4*)(wf + (size_t)rstart[tid] * WF_SLOT_SHORTS);
        for (int q = 0; q < WF_SLOT_SHORTS / 8; ++q) dst[q] = z;
    }
}

// ---------------------------------------------------------------------------
// Prep 2: W fp32 -> bf16 32x32-MFMA B-fragments in SCHEDULE order.
// For k-half h: frag[j] = W[b][n=lane&31][h*16 + (lane>>5)*8 + j]
// at wf[pos*1024 + h*512 + lane*8 + j]. Reads 32 B contiguous, writes 16 B.
// ---------------------------------------------------------------------------
__global__ void prep_w_kernel(const float* __restrict__ wd, const int* __restrict__ pos_of,
                              short* __restrict__ wf)
{
    const int g = blockIdx.x * blockDim.x + threadIdx.x;  // 32768 threads
    const int lane = g & 63;
    const int h = (g >> 6) & 1;
    const int b = g >> 7;
    const int pos = pos_of[b];
    const float* src = wd + (size_t)b * (BH * BW) + (lane & 31) * BW + h * 16 + (lane >> 5) * 8;
    const float4 w0 = *(const float4*)src;
    const float4 w1 = *(const float4*)(src + 4);
    short8 o;
    o[0] = f2bf(w0.x); o[1] = f2bf(w0.y); o[2] = f2bf(w0.z); o[3] = f2bf(w0.w);
    o[4] = f2bf(w1.x); o[5] = f2bf(w1.y); o[6] = f2bf(w1.z); o[7] = f2bf(w1.w);
    *(short8*)(wf + (size_t)pos * WF_SLOT_SHORTS + h * 512 + lane * 8) = o;
}

// ---------------------------------------------------------------------------
// Main: 256 WGs x 1024 thr (16 waves), LDS ~131 KB -> 1 WG/CU = 16 waves/CU,
// single full pass. WG owns 64 tokens (2 groups of 32). Wave w walks bucket
// w's contiguous schedule segment: per entry 4x mfma_f32_32x32x16_bf16
// (2 token-groups x 2 k-halves), 2 wf loads (L2 stream, address = pure fn of
// loop index), 4 LDS A-frag reads. 1-deep software pipeline; bias rolls one
// row ahead via the next entry's row field.
// ---------------------------------------------------------------------------
__global__ __launch_bounds__(1024, 4) void spmm_main_kernel(
    const float* __restrict__ x, const float* __restrict__ bias,
    const short* __restrict__ wf, const int* __restrict__ sched_g,
    const int* __restrict__ wstart_g, float* __restrict__ out)
{
    __shared__ short xs[T_TILE * XS_STRIDE];   // 133120 B
    __shared__ int ssched[SCHED_ALLOC];        // 1216 B
    __shared__ int swstart[NBUCKET + 1];

    const int tid = threadIdx.x;
    const int n0 = blockIdx.x * T_TILE;

    // Stage x tile -> LDS bf16: 8 rows in flight (128 thr/row x 8 cols),
    // coalesced dwordx4 pairs, short8 stores, conflict-free stride.
    {
        const int tr = tid >> 7;       // 0..7
        const int tc = tid & 127;      // col octet
        const float* xp = x + (size_t)(n0 + tr) * IN_F + tc * 8;
        short* sp = xs + tr * XS_STRIDE + tc * 8;
#pragma unroll
        for (int it = 0; it < T_TILE / 8; ++it) {
            const float4 a = *(const float4*)xp;
            const float4 b = *(const float4*)(xp + 4);
            short8 s;
            s[0] = f2bf(a.x); s[1] = f2bf(a.y); s[2] = f2bf(a.z); s[3] = f2bf(a.w);
            s[4] = f2bf(b.x); s[5] = f2bf(b.y); s[6] = f2bf(b.z); s[7] = f2bf(b.w);
            *(short8*)sp = s;
            xp += 8 * IN_F;
            sp += 8 * XS_STRIDE;
        }
    }
    if (tid < SCHED_ALLOC) ssched[tid] = sched_g[tid];
    if (tid < NBUCKET + 1) swstart[tid] = wstart_g[tid];
    __syncthreads();

    const int lane = tid & 63;
    const int wave = tid >> 6;         // 0..15 == bucket
    const int l32 = lane & 31;
    const int kg = lane >> 5;          // k-group (0/1)

    const int s = swstart[wave];
    const int e = swstart[wave + 1];   // length >= 2 (two rows per bucket)

    // A-frag base: A[m=l32][k = h*16 + kg*8 + j] = xs[tg*32+l32][c*32 + k]
    const short* xA = xs + l32 * XS_STRIDE + kg * 8;   // + tg*32*XS_STRIDE + c*32 + h*16
    const short* wfl = wf + lane * 8;                  // + slot*1024 + h*512

    // ---- prologue: entry s fully loaded ----
    int e0 = ssched[s];
    int e1 = ssched[s + 1];
    {
    }
    const int c0 = (e0 & 31) * BW;
    short8 wh0 = *(const short8*)(wfl + (size_t)s * WF_SLOT_SHORTS);
    short8 wh1 = *(const short8*)(wfl + (size_t)s * WF_SLOT_SHORTS + 512);
    short8 a00 = *(const short8*)(xA + c0);                          // tg0, h0
    short8 a01 = *(const short8*)(xA + c0 + 16);                     // tg0, h1
    short8 a10 = *(const short8*)(xA + 32 * XS_STRIDE + c0);         // tg1, h0
    short8 a11 = *(const short8*)(xA + 32 * XS_STRIDE + c0 + 16);    // tg1, h1

    float bv = bias[((e0 >> 5) & 31) * BH + l32];

    const float16v zero16 = {0.f,0.f,0.f,0.f, 0.f,0.f,0.f,0.f, 0.f,0.f,0.f,0.f, 0.f,0.f,0.f,0.f};
    float16v acc0 = zero16;   // tokens n0 + 0..31
    float16v acc1 = zero16;   // tokens n0 + 32..63

    for (int k = s; k < e; ++k) {
        // prefetch entry k+1 (pads make every access unconditionally safe)
        const int en = ssched[k + 2];
        const int cn = (e1 & 31) * BW;
        const short8 nwh0 = *(const short8*)(wfl + (size_t)(k + 1) * WF_SLOT_SHORTS);
        const short8 nwh1 = *(const short8*)(wfl + (size_t)(k + 1) * WF_SLOT_SHORTS + 512);
        const short8 na00 = *(const short8*)(xA + cn);
        const short8 na01 = *(const short8*)(xA + cn + 16);
        const short8 na10 = *(const short8*)(xA + 32 * XS_STRIDE + cn);
        const short8 na11 = *(const short8*)(xA + 32 * XS_STRIDE + cn + 16);

        acc0 = __builtin_amdgcn_mfma_f32_32x32x16_bf16(a00, wh0, acc0, 0, 0, 0);
        acc0 = __builtin_amdgcn_mfma_f32_32x32x16_bf16(a01, wh1, acc0, 0, 0, 0);
        acc1 = __builtin_amdgcn_mfma_f32_32x32x16_bf16(a10, wh0, acc1, 0, 0, 0);
        acc1 = __builtin_amdgcn_mfma_f32_32x32x16_bf16(a11, wh1, acc1, 0, 0, 0);

        if (e0 & FLUSH_BIT) {          // wave-uniform: last entry of row rr
            const int rr = (e0 >> 5) & 31;
            const int ob = rr * BH + l32;
            float* op0 = out + (size_t)n0 * OUT_F + ob;
#pragma unroll
            for (int reg = 0; reg < 16; ++reg) {
                // token row within group = (reg&3) + 8*(reg>>2) + 4*kg  [m74]
                const int row = (reg & 3) + 8 * (reg >> 2) + 4 * kg;
                op0[(size_t)row * OUT_F] = acc0[reg] + bv;
                op0[(size_t)(row + 32) * OUT_F] = acc1[reg] + bv;
            }
            acc0 = zero16;
            acc1 = zero16;
            bv = bias[((e1 >> 5) & 31) * BH + l32];   // next row's bias (pad row 0 harmless)
        }
        e0 = e1; e1 = en;
        a00 = na00; a01 = na01; a10 = na10; a11 = na11;
        wh0 = nwh0; wh1 = nwh1;
    }
}

extern "C" void kernel_launch(void* const* d_in, const int* in_sizes, int n_in,
                              void* d_out, int out_size, void* d_ws, size_t ws_size,
                              hipStream_t stream) {
    const float* x    = (const float*)d_in[0];
    const float* wd   = (const float*)d_in[1];
    const float* bias = (const float*)d_in[2];
    const int* brow   = (const int*)d_in[3];
    const int* bcol   = (const int*)d_in[4];
    float* out = (float*)d_out;

    char* ws = (char*)d_ws;                 // needs ~625 KB
    short* wf   = (short*)ws;
    int* sched  = (int*)(ws + WS_SCHED_OFF);
    int* pos_of = (int*)(ws + WS_POS_OFF);
    int* wstart = (int*)(ws + WS_WSTART_OFF);

    prep_sched_kernel<<<1, 256, 0, stream>>>(brow, bcol, sched, pos_of, wstart, wf);
    prep_w_kernel<<<NB * 128 / 256, 256, 0, stream>>>(wd, pos_of, wf);
    spmm_main_kernel<<<N_TOKENS / T_TILE, 1024, 0, stream>>>(x, bias, wf, sched, wstart, out);
}